// Round 1
// 213.263 us; speedup vs baseline: 1.1076x; 1.1076x over previous
//
#include <hip/hip_runtime.h>
#include <hip/hip_bf16.h>
#include <cstdint>
#include <cstddef>

typedef __bf16 bf16x8 __attribute__((ext_vector_type(8)));
typedef __bf16 bf16x4 __attribute__((ext_vector_type(4)));
typedef float f32x4 __attribute__((ext_vector_type(4)));

#define BATCH 16
#define MDIM 1024
#define NDIM 4096
#define KDIM 1024
#define BM 256
#define BN 256
#define BK 64
#define NKT (KDIM / BK)  // 16

__device__ __forceinline__ void gload_lds16(const void* g, void* l) {
  __builtin_amdgcn_global_load_lds(
      (const __attribute__((address_space(1))) void*)g,
      (__attribute__((address_space(3))) void*)l, 16, 0, 0);
}

#define BAR() __builtin_amdgcn_s_barrier()
#define SB() __builtin_amdgcn_sched_barrier(0)
#define FENCE() asm volatile("" ::: "memory")
#define LGKM0()                                        \
  do {                                                 \
    asm volatile("s_waitcnt lgkmcnt(0)" ::: "memory"); \
    SB();                                              \
  } while (0)
#define VMC32()                                        \
  do {                                                 \
    asm volatile("s_waitcnt vmcnt(32)" ::: "memory");  \
    SB();                                              \
  } while (0)
#define VMC0()                                         \
  do {                                                 \
    asm volatile("s_waitcnt vmcnt(0)" ::: "memory");   \
    SB();                                              \
  } while (0)

// ---------------------------------------------------------------------------
// Kernel 1: W~[b][o][i] bf16 into workspace (~10us).  (unchanged)
// ---------------------------------------------------------------------------
__global__ __launch_bounds__(256) void modw_kernel(
    const float* __restrict__ weight, const float* __restrict__ y,
    __bf16* __restrict__ wm) {
  const int blk = blockIdx.x;  // 16384
  const int b = blk & 15;
  const int o = blk >> 4;
  const int t = threadIdx.x;
  const float4 w4 = reinterpret_cast<const float4*>(weight + (size_t)o * KDIM)[t];
  const float4 y4 = reinterpret_cast<const float4*>(y + (size_t)b * KDIM)[t];
  const float p0 = w4.x * y4.x, p1 = w4.y * y4.y;
  const float p2 = w4.z * y4.z, p3 = w4.w * y4.w;
  float s = p0 * p0 + p1 * p1 + p2 * p2 + p3 * p3;
#pragma unroll
  for (int off = 32; off >= 1; off >>= 1) s += __shfl_xor(s, off, 64);
  __shared__ float ps[4];
  if ((t & 63) == 0) ps[t >> 6] = s;
  __syncthreads();
  const float tot = ps[0] + ps[1] + ps[2] + ps[3];
  const float scale = 0.03125f;  // 1/sqrt(1024)
  const float dn = scale * rsqrtf(scale * scale * tot + 1e-8f);
  bf16x4 v;
  v[0] = (__bf16)(p0 * dn);
  v[1] = (__bf16)(p1 * dn);
  v[2] = (__bf16)(p2 * dn);
  v[3] = (__bf16)(p3 * dn);
  *reinterpret_cast<bf16x4*>(wm + ((size_t)b * MDIM + o) * KDIM + t * 4) = v;
}

// ---------------------------------------------------------------------------
// Kernel 2: 256x256x64, 8 waves (2x4).  Relaxed schedule: ONE barrier + one
// counted vmcnt + one lgkm drain per K-tile (was 16 barriers / 8 drains per
// 2 K-tiles).  Compiler + 2-wave drift overlap LDS traffic with MFMA.
// Per-wave VMEM queue invariant at the counted wait:
//   [A-stage (4, older), B loads (32, younger)]  ->  vmcnt(32) drains stage.
// Order pinned by FENCE (memory-clobber asm) between stageA and loadB.
// ---------------------------------------------------------------------------
__global__ __launch_bounds__(512, 2) void gemm_kernel(
    const __bf16* __restrict__ Wm, const float* __restrict__ E,
    float* __restrict__ out) {
  const int orig = blockIdx.x;  // 1024
  const int wg = (orig & 7) * 128 + (orig >> 3);  // bijective XCD swizzle
  const int mt = wg & 3;
  const int nt = (wg >> 2) & 15;
  const int b = wg >> 6;
  const int m0 = mt * BM, n0 = nt * BN;

  __shared__ __align__(16) char smem[131072];
  char* const A0_ = smem;
  char* const A1_ = smem + 32768;
  char* const B0_ = smem + 65536;
  char* const B1_ = smem + 98304;

  const int tid = threadIdx.x;  // 512
  const int lane = tid & 63;
  const int wid = tid >> 6;  // 0..7
  const int wr = wid >> 2;   // 0..1
  const int wc = wid & 3;    // 0..3
  const int ml = lane & 15;
  const int kg = lane >> 4;

  // ---- A staging ----
  const int arow = tid >> 3;                      // 0..63, +64/round
  const int aswz = ((tid & 7) ^ (arow & 7)) * 8;  // pre-swizzled k-elem off
  const __bf16* Ag = Wm + ((size_t)(b * MDIM + m0 + arow)) * KDIM + aswz;
  const int aldsOff = tid * 16;

  // ---- B staging ----
  const int bn1 = tid & 63;
  const int bkg = tid >> 6;
  typedef const __attribute__((address_space(1))) float gfloat;
  gfloat* Eg = (gfloat*)(E + (size_t)b * KDIM * NDIM +
                         (size_t)(bkg * 8) * NDIM + n0 + bn1);
  int bwr[4];
#pragma unroll
  for (int c = 0; c < 4; ++c) {
    const int n = bn1 + 64 * c;
    bwr[c] = n * 128 + ((bkg * 16) ^ ((n & 7) << 4));
  }

  // ---- compute-side fragment addressing ----
  const int colA = (kg * 16) ^ ((ml & 7) << 4);
  const int arB = (wr * 128 + ml) * 128;
  const int brB = (wc * 64 + ml) * 128;

  f32x4 acc[8][4];
#pragma unroll
  for (int i = 0; i < 8; ++i)
#pragma unroll
    for (int j = 0; j < 4; ++j) acc[i][j] = (f32x4){0.f, 0.f, 0.f, 0.f};

  auto stageA = [&](char* Ab, int kt) {
#pragma unroll
    for (int r = 0; r < 4; ++r)
      gload_lds16(Ag + (size_t)(64 * r) * KDIM + kt * BK,
                  Ab + aldsOff + r * 8192);
  };
  auto loadB = [&](float (&brr)[4][8], int kt) {
#pragma unroll
    for (int c = 0; c < 4; ++c)
#pragma unroll
      for (int j = 0; j < 8; ++j)
        brr[c][j] = Eg[(size_t)(kt * BK + j) * NDIM + 64 * c];
  };
  auto writeB = [&](char* Bb, float (&brr)[4][8]) {
#pragma unroll
    for (int c = 0; c < 4; ++c) {
      bf16x8 v;
#pragma unroll
      for (int j = 0; j < 8; ++j) v[j] = (__bf16)brr[c][j];
      *reinterpret_cast<bf16x8*>(Bb + bwr[c]) = v;
    }
  };

  float br[4][8];  // B reg-stage, persistent across iterations

  // ---- prologue: A0/B0 <- tile 0 (full drain, once); br <- tile 1 ----
  {
    float brT[4][8];
    stageA(A0_, 0);  // queue [A0(4)]
    FENCE();
    SB();
    loadB(brT, 0);     // queue [A0(4), brT(32)]
    writeB(B0_, brT);  // auto-wait drains everything (prologue only)
    loadB(br, 1);      // queue [br1(32)]  == loop entry invariant
    LGKM0();
    BAR();
  }

  char* Ac = A0_;
  char* Ao = A1_;
  char* Bc = B0_;
  char* Bo = B1_;

#pragma unroll 1
  for (int t = 0; t < NKT; ++t) {
    // --- publish tile t+1 into the "other" buffers; prefetch tile t+2 ---
    if (t + 1 < NKT) {
      writeB(Bo, br);    // auto vmcnt wait: br (tile t+1) loads done
      stageA(Ao, t + 1); // 4 gload_lds, must precede loadB in VMEM order
      FENCE();
      SB();
    }
    if (t + 2 < NKT) loadB(br, t + 2);  // 32 loads, stay in flight

    // --- compute tile t from Ac/Bc (no internal barriers; compiler +
    //     2-wave drift overlap ds_read / VMEM issue / cvt with MFMA) ---
#pragma unroll
    for (int kk = 0; kk < 2; ++kk) {
      const int kx = colA ^ (kk * 64);
      bf16x8 af[4], bf[4];
#pragma unroll
      for (int nf = 0; nf < 4; ++nf)
        bf[nf] = *reinterpret_cast<const bf16x8*>(Bc + brB + nf * 2048 + kx);
#pragma unroll
      for (int i = 0; i < 4; ++i)
        af[i] = *reinterpret_cast<const bf16x8*>(Ac + arB + i * 2048 + kx);
      __builtin_amdgcn_s_setprio(1);
#pragma unroll
      for (int i = 0; i < 4; ++i)
#pragma unroll
        for (int nf = 0; nf < 4; ++nf)
          acc[i][nf] = __builtin_amdgcn_mfma_f32_16x16x32_bf16(
              af[i], bf[nf], acc[i][nf], 0, 0, 0);
      __builtin_amdgcn_s_setprio(0);
#pragma unroll
      for (int i = 0; i < 4; ++i)
        af[i] = *reinterpret_cast<const bf16x8*>(Ac + arB + (4 + i) * 2048 + kx);
      __builtin_amdgcn_s_setprio(1);
#pragma unroll
      for (int i = 0; i < 4; ++i)
#pragma unroll
        for (int nf = 0; nf < 4; ++nf)
          acc[4 + i][nf] = __builtin_amdgcn_mfma_f32_16x16x32_bf16(
              af[i], bf[nf], acc[4 + i][nf], 0, 0, 0);
      __builtin_amdgcn_s_setprio(0);
    }

    // --- single sync point per K-tile ---
    if (t + 2 < NKT) {
      VMC32();  // queue [Ao-stage(4), br(32)] -> drains the A stage only
    } else {
      VMC0();   // tail: no br loads in flight; drain remaining stage
    }
    LGKM0();    // my B ds_writes visible (+ all frag reads done)
    BAR();      // flip: Ao/Bo become current

    char* ta = Ac; Ac = Ao; Ao = ta;
    char* tb = Bc; Bc = Bo; Bo = tb;
  }

  // ---- epilogue (unchanged) ----
  float* ob = out + ((size_t)(b * MDIM + m0 + wr * 128 + kg * 4)) * NDIM +
              n0 + wc * 64 + ml;
#pragma unroll
  for (int mf = 0; mf < 8; ++mf)
#pragma unroll
    for (int nf = 0; nf < 4; ++nf) {
      const f32x4 a = acc[mf][nf];
      float* p = ob + (size_t)mf * 16 * NDIM + nf * 16;
#pragma unroll
      for (int q = 0; q < 4; ++q) p[(size_t)q * NDIM] = a[q];
    }
}

extern "C" void kernel_launch(void* const* d_in, const int* in_sizes, int n_in,
                              void* d_out, int out_size, void* d_ws,
                              size_t ws_size, hipStream_t stream) {
  (void)in_sizes;
  (void)n_in;
  (void)out_size;
  (void)ws_size;
  const float* Efou = (const float*)d_in[0];
  const float* y = (const float*)d_in[1];
  const float* weight = (const float*)d_in[2];
  float* outp = (float*)d_out;
  __bf16* wm = (__bf16*)d_ws;  // 32 MB

  modw_kernel<<<dim3(BATCH * MDIM), dim3(256), 0, stream>>>(weight, y, wm);
  gemm_kernel<<<dim3(BATCH * (MDIM / BM) * (NDIM / BN)), dim3(512), 0,
                stream>>>(wm, Efou, outp);
}